// Round 22
// baseline (306.699 us; speedup 1.0000x reference)
//
#include <hip/hip_runtime.h>

#define T_ 10
#define B_ 4
#define N_ 2048
#define NTOT 8192
#define F_ 64
#define H_ 128
#define NHEADS 4
#define D_ 32
#define E_ 65536
#define EF 73728          // E + NTOT self-loops
#define HPAD 136

typedef __bf16 bf16x8 __attribute__((ext_vector_type(8)));
typedef float f32x4 __attribute__((ext_vector_type(4)));
typedef unsigned short u16;
typedef unsigned int u32;

__device__ __forceinline__ float bf2f(u16 u){
  union { unsigned int i; float f; } v; v.i = ((unsigned int)u) << 16; return v.f;
}
__device__ __forceinline__ u16 f2bf(float f){
  union { float f; unsigned int i; } v; v.f = f;
  return (u16)((v.i + 0x7FFFu + ((v.i >> 16) & 1u)) >> 16);
}
__device__ __forceinline__ float rcpf(float x){ return __builtin_amdgcn_rcpf(x); }
__device__ __forceinline__ float sigf(float x){ return rcpf(1.f + __expf(-x)); }
__device__ __forceinline__ float tanhfast(float x){ return 1.f - 2.f * rcpf(__expf(2.f * x) + 1.f); }
__device__ __forceinline__ float lrelu(float x){ return x > 0.f ? x : 0.2f * x; }

// ---------------- CSR build ----------------
__global__ __launch_bounds__(256) void k_init(int* __restrict__ cnt){
  int i = blockIdx.x * 256 + threadIdx.x;
  if(i < NTOT) cnt[i] = 0;
}

__global__ __launch_bounds__(256) void k_count(const int* __restrict__ ei, int* __restrict__ cnt){
  int e = blockIdx.x * 256 + threadIdx.x;
  if(e < E_) atomicAdd(&cnt[ei[E_ + e]], 1);
}

__global__ __launch_bounds__(1024) void k_scan(const int* __restrict__ cnt,
                                               int* __restrict__ rowst,
                                               int* __restrict__ cursor){
  __shared__ int lds[1024];
  const int t = threadIdx.x;
  int loc[8];
  int s = 0;
  #pragma unroll
  for(int i = 0; i < 8; i++){ loc[i] = s; s += cnt[t * 8 + i]; }
  lds[t] = s;
  __syncthreads();
  for(int off = 1; off < 1024; off <<= 1){
    int v = lds[t];
    int a = (t >= off) ? lds[t - off] : 0;
    __syncthreads();
    lds[t] = v + a;
    __syncthreads();
  }
  const int base = (t > 0) ? lds[t - 1] : 0;
  #pragma unroll
  for(int i = 0; i < 8; i++){
    rowst[t * 8 + i] = base + loc[i];
    cursor[t * 8 + i] = 0;
  }
  if(t == 1023) rowst[NTOT] = lds[1023];
}

__global__ __launch_bounds__(256) void k_fill(const int* __restrict__ ei,
                                              const int* __restrict__ rowst,
                                              int* __restrict__ cursor,
                                              int* __restrict__ csr,
                                              int* __restrict__ csr_dst){
  int e = blockIdx.x * 256 + threadIdx.x;
  if(e < E_){
    int d = ei[E_ + e];
    int pos = atomicAdd(&cursor[d], 1);
    csr[rowst[d] + pos] = ei[e];
    csr_dst[rowst[d] + pos] = d;
  }
}

// ---- weight conversions: y=0..3 gate-permuted LSTM mats; y=4 GAT W^T ----
__global__ __launch_bounds__(256) void k_wconv(const float* __restrict__ s0, u16* __restrict__ d0,
                                               const float* __restrict__ s1, u16* __restrict__ d1,
                                               const float* __restrict__ s2, u16* __restrict__ d2,
                                               const float* __restrict__ s3, u16* __restrict__ d3,
                                               const float* __restrict__ W, u16* __restrict__ Wt){
  int i = blockIdx.x * 256 + threadIdx.x;
  if(blockIdx.y == 4){
    if(i < H_ * F_){
      int nn = i >> 6, f = i & 63;
      Wt[i] = f2bf(W[f * H_ + nn]);
    }
    return;
  }
  const float* src = blockIdx.y == 0 ? s0 : blockIdx.y == 1 ? s1 : blockIdx.y == 2 ? s2 : s3;
  u16* dst = blockIdx.y == 0 ? d0 : blockIdx.y == 1 ? d1 : blockIdx.y == 2 ? d2 : d3;
  if(i < 512 * 128){
    int p = i >> 7, k = i & 127;
    int w = p >> 6, g = (p >> 4) & 3, l = p & 15;
    int row = g * 128 + w * 16 + l;
    dst[i] = f2bf(src[row * 128 + k]);
  }
}

// ---------------- MFMA GAT projection + attention coefficients ----------------
__global__ __launch_bounds__(256) void k_projm(const float* __restrict__ x,
    const u16* __restrict__ Wt, const float* __restrict__ att_s, const float* __restrict__ att_d,
    u16* __restrict__ hbuf, float* __restrict__ asrc, float* __restrict__ adst){
  const int tid  = threadIdx.x;
  const int wave = tid >> 6;
  const int lane = tid & 63;
  const int l15  = lane & 15;
  const int quad = lane >> 4;
  const int r0   = blockIdx.x * 64 + wave * 16;
  const int row  = r0 + l15;
  const int t = row >> 13, nt = row & 8191;
  const int b = nt >> 11, n = nt & 2047;
  const float* xrow = x + (((size_t)b * T_ + t) * N_ + n) * F_;

  bf16x8 a[2];
  #pragma unroll
  for(int ks = 0; ks < 2; ks++){
    const float4 f0 = *(const float4*)(xrow + ks * 32 + quad * 8);
    const float4 f1 = *(const float4*)(xrow + ks * 32 + quad * 8 + 4);
    bf16x8 av;
    av[0] = (__bf16)f0.x; av[1] = (__bf16)f0.y; av[2] = (__bf16)f0.z; av[3] = (__bf16)f0.w;
    av[4] = (__bf16)f1.x; av[5] = (__bf16)f1.y; av[6] = (__bf16)f1.z; av[7] = (__bf16)f1.w;
    a[ks] = av;
  }

  f32x4 acc[8];
  #pragma unroll
  for(int c = 0; c < 8; c++){ f32x4 z = {0.f,0.f,0.f,0.f}; acc[c] = z; }
  #pragma unroll
  for(int c = 0; c < 8; c++){
    #pragma unroll
    for(int ks = 0; ks < 2; ks++){
      const bf16x8 bv = *(const bf16x8*)(Wt + (c * 16 + l15) * F_ + ks * 32 + quad * 8);
      acc[c] = __builtin_amdgcn_mfma_f32_16x16x32_bf16(a[ks], bv, acc[c], 0, 0, 0);
    }
  }

  float ps[4][4], pd[4][4];   // [r][head]
  #pragma unroll
  for(int r = 0; r < 4; r++)
    #pragma unroll
    for(int h = 0; h < 4; h++){ ps[r][h] = 0.f; pd[r][h] = 0.f; }

  #pragma unroll
  for(int c = 0; c < 8; c++){
    const int col = c * 16 + l15;
    const float asv = att_s[col];
    const float adv = att_d[col];
    const int head = c >> 1;
    #pragma unroll
    for(int r = 0; r < 4; r++){
      const float v = acc[c][r];
      hbuf[(size_t)(r0 + quad * 4 + r) * H_ + col] = f2bf(v);
      ps[r][head] += v * asv;
      pd[r][head] += v * adv;
    }
  }
  #pragma unroll
  for(int m = 8; m >= 1; m >>= 1){
    #pragma unroll
    for(int r = 0; r < 4; r++)
      #pragma unroll
      for(int h = 0; h < 4; h++){
        ps[r][h] += __shfl_xor(ps[r][h], m);
        pd[r][h] += __shfl_xor(pd[r][h], m);
      }
  }
  if(l15 == 0){
    #pragma unroll
    for(int r = 0; r < 4; r++){
      const int rw = r0 + quad * 4 + r;
      #pragma unroll
      for(int h = 0; h < 4; h++){
        asrc[(size_t)rw * NHEADS + h] = ps[r][h];
        adst[(size_t)rw * NHEADS + h] = pd[r][h];
      }
    }
  }
}

// ---------------- fused GAT softmax + aggregation (v4: dword-lane layout) ------------
// R20: j-loop did two 2-byte hbuf loads per lane per edge (worst coalescing grain).
// v4 remaps lane -> dims (2*lane, 2*lane+1); both dims share head = lane>>4, so each
// edge iteration is ONE dword load (256B/wave, fully coalesced) + one LDS broadcast
// + 2 FMA. Output packs two bf16 into one dword store. Same no-max single-pass
// softmax (R19-proven numerically safe for bounded scores).
__global__ __launch_bounds__(256) void k_gat(const u16* __restrict__ hbuf,
    const float* __restrict__ asrc, const float* __restrict__ adst,
    const int* __restrict__ rowst, const int* __restrict__ csr,
    const float* __restrict__ gbias, u16* __restrict__ spat){
  __shared__ float exl[4][64][4];   // per-wave edge numerators
  __shared__ int   sxl[4][64];      // per-wave edge sources
  const int tid = threadIdx.x;
  const int wave = tid >> 6;
  const int lane = tid & 63;
  const int task = blockIdx.x * 4 + wave;
  const int node = task & 8191;
  const int t = task >> 13;
  const int rbase = t * NTOT;
  const int rs = rowst[node], re = rowst[node + 1];
  const int head = lane >> 4;           // dims 2*lane, 2*lane+1 both in this head

  const float4 ad4  = *(const float4*)&adst[(size_t)(rbase + node) * NHEADS];
  const float4 ass4 = *(const float4*)&asrc[(size_t)(rbase + node) * NHEADS];
  const float xs0 = __expf(lrelu(ass4.x + ad4.x));
  const float xs1 = __expf(lrelu(ass4.y + ad4.y));
  const float xs2 = __expf(lrelu(ass4.z + ad4.z));
  const float xs3 = __expf(lrelu(ass4.w + ad4.w));

  float den0 = 0.f, den1 = 0.f, den2 = 0.f, den3 = 0.f;
  float acc0 = 0.f, acc1 = 0.f;
  for(int base = rs; base < re; base += 64){
    const int i = base + lane;
    float ex0 = 0.f, ex1 = 0.f, ex2 = 0.f, ex3 = 0.f;
    int sv = 0;
    if(i < re){
      sv = csr[i];
      const float4 a2 = *(const float4*)&asrc[(size_t)(rbase + sv) * NHEADS];
      ex0 = __expf(lrelu(a2.x + ad4.x)); ex1 = __expf(lrelu(a2.y + ad4.y));
      ex2 = __expf(lrelu(a2.z + ad4.z)); ex3 = __expf(lrelu(a2.w + ad4.w));
      den0 += ex0; den1 += ex1; den2 += ex2; den3 += ex3;
    }
    exl[wave][lane][0] = ex0; exl[wave][lane][1] = ex1;
    exl[wave][lane][2] = ex2; exl[wave][lane][3] = ex3;
    sxl[wave][lane] = sv;
    __asm__ volatile("s_waitcnt lgkmcnt(0)" ::: "memory");
    __builtin_amdgcn_sched_barrier(0);
    const int lim = (re - base < 64) ? (re - base) : 64;
    for(int j = 0; j < lim; j++){
      const int s = sxl[wave][j];
      const float ex = exl[wave][j][head];
      const u32 pv = *(const u32*)(hbuf + (size_t)(rbase + s) * H_ + 2 * lane);
      acc0 += ex * bf2f((u16)(pv & 0xFFFFu));
      acc1 += ex * bf2f((u16)(pv >> 16));
    }
  }
  #pragma unroll
  for(int msk = 32; msk >= 1; msk >>= 1){
    den0 += __shfl_xor(den0, msk); den1 += __shfl_xor(den1, msk);
    den2 += __shfl_xor(den2, msk); den3 += __shfl_xor(den3, msk);
  }
  den0 += xs0; den1 += xs1; den2 += xs2; den3 += xs3;

  const float denh = head == 0 ? den0 : head == 1 ? den1 : head == 2 ? den2 : den3;
  const float xsh  = head == 0 ? xs0  : head == 1 ? xs1  : head == 2 ? xs2  : xs3;
  const float rd = rcpf(denh);
  {
    const u32 pv = *(const u32*)(hbuf + (size_t)(rbase + node) * H_ + 2 * lane);
    acc0 += xsh * bf2f((u16)(pv & 0xFFFFu));
    acc1 += xsh * bf2f((u16)(pv >> 16));
  }
  const float2 gb = *(const float2*)(gbias + 2 * lane);
  float v0 = acc0 * rd + gb.x;
  float v1 = acc1 * rd + gb.y;
  v0 = v0 > 0.f ? v0 : 0.f;
  v1 = v1 > 0.f ? v1 : 0.f;
  const u32 po = (u32)f2bf(v0) | ((u32)f2bf(v1) << 16);
  *(u32*)(spat + (size_t)(rbase + node) * H_ + 2 * lane) = po;
}

// ---------------- 2-layer LSTM: R14 best (3-bank/16-phase, cst/bias in LDS) ------
// FROZEN at 133us (R19 proved the 197MB scratch is latency-hidden; clean-memory
// variant was SLOWER at 144us — barrier chain is the floor for this shape).
__global__ __launch_bounds__(512) void k_lstm(
    const u16* __restrict__ spat,
    const u16* __restrict__ Wp_ih0, const u16* __restrict__ Wp_hh0,
    const float* __restrict__ bih0, const float* __restrict__ bhh0,
    const u16* __restrict__ Wp_ih1, const u16* __restrict__ Wp_hh1,
    const float* __restrict__ bih1, const float* __restrict__ bhh1,
    const float* __restrict__ lng, const float* __restrict__ lnb,
    float* __restrict__ out)
{
  __shared__ __align__(16) u16 xin[32 * HPAD];               // 8.5 KB
  __shared__ __align__(16) u16 h0s[2][32 * HPAD];            // 17 KB
  __shared__ __align__(16) u16 h1s[2][32 * HPAD];            // 17 KB
  __shared__ __align__(16) float hfin[32 * 129];             // 16.5 KB fp32 final h1
  __shared__ float cst_l[16][512];                           // 32 KB per-thread cell state
  __shared__ float bias_l[8][512];                           // 16 KB per-thread gate bias

  const int tid  = threadIdx.x;
  const int wave = tid >> 6;
  const int lane = tid & 63;
  const int l15  = lane & 15;
  const int quad = lane >> 4;
  const int n0   = blockIdx.x * 32;
  const int dim  = wave * 16 + l15;

  for(int i = tid; i < 2 * 32 * HPAD; i += 512){
    ((u16*)h0s)[i] = 0; ((u16*)h1s)[i] = 0;
  }
  // xin(t=0): 32 rows x 16 chunks of 16B = 512 chunks = one pass of 512 threads
  {
    const u16* src = spat + (size_t)n0 * H_;
    const int r = tid >> 4, c = tid & 15;
    *(uint4*)(xin + r * HPAD + c * 8) = *(const uint4*)(src + r * 128 + c * 8);
  }
  #pragma unroll
  for(int i = 0; i < 16; i++) cst_l[i][tid] = 0.f;
  #pragma unroll
  for(int g = 0; g < 4; g++){
    bias_l[g][tid]     = bih0[g * 128 + dim] + bhh0[g * 128 + dim];
    bias_l[4 + g][tid] = bih1[g * 128 + dim] + bhh1[g * 128 + dim];
  }
  __syncthreads();

  // lane's fragment base: rows wave*64 + nt*16 + l15 of the gate-permuted matrix,
  // elements quad*8..quad*8+7 of k-slice ks -> Wm[fbase + nt*2048 + ks*32]
  const size_t fbase = (size_t)(wave * 64 + l15) * 128 + quad * 8;

// 3-bank/16-phase pipeline pieces. All indices compile-time static (rule #20).
#define LOADB(BK, MATB, KS, NTO)                                          \
    BK[0] = *(const bf16x8*)((MATB) + (NTO) * 2048 + (KS) * 32);          \
    BK[1] = *(const bf16x8*)((MATB) + ((NTO) + 1) * 2048 + (KS) * 32);

#define LOADA(AP, KS)                                                     \
    a0 = *(const bf16x8*)((AP) + l15 * HPAD + (KS) * 32 + quad * 8);      \
    a1 = *(const bf16x8*)((AP) + (16 + l15) * HPAD + (KS) * 32 + quad * 8);

#define MM(BK, NTO)                                                                             \
    acc[0][NTO]       = __builtin_amdgcn_mfma_f32_16x16x32_bf16(a0, BK[0], acc[0][NTO], 0, 0, 0);       \
    acc[1][NTO]       = __builtin_amdgcn_mfma_f32_16x16x32_bf16(a1, BK[0], acc[1][NTO], 0, 0, 0);       \
    acc[0][(NTO) + 1] = __builtin_amdgcn_mfma_f32_16x16x32_bf16(a0, BK[1], acc[0][(NTO) + 1], 0, 0, 0); \
    acc[1][(NTO) + 1] = __builtin_amdgcn_mfma_f32_16x16x32_bf16(a1, BK[1], acc[1][(NTO) + 1], 0, 0, 0); \
    __builtin_amdgcn_sched_barrier(0);

  #pragma unroll 1
  for(int t = 0; t < T_; t++){
    const int rp = t & 1, wp = rp ^ 1;
    #pragma unroll
    for(int layer = 0; layer < 2; layer++){
      const u16* Wih = layer ? Wp_ih1 : Wp_ih0;
      const u16* Whh = layer ? Wp_hh1 : Wp_hh0;
      const u16* xp  = layer ? h0s[wp] : xin;      // a-input, x-part (phases 0-7)
      const u16* hp  = layer ? h1s[rp] : h0s[rp];  // a-input, h-part (phases 8-15)

      f32x4 acc[2][4];
      #pragma unroll
      for(int nt = 0; nt < 4; nt++){
        const float bv = bias_l[layer * 4 + nt][tid];
        f32x4 b4 = {bv, bv, bv, bv};
        acc[0][nt] = b4; acc[1][nt] = b4;
      }

      const u16* WihB = Wih + fbase;
      const u16* WhhB = Whh + fbase;
      bf16x8 bA[2], bB[2], bC[2];
      bf16x8 a0, a1;

      // prologue: first two banks + ks0 a-frags
      LOADB(bA, WihB, 0, 0)  LOADB(bB, WihB, 0, 2)  LOADA(xp, 0)
      // 16 phases; bank loaded at phase p is consumed at p+2
      LOADB(bC, WihB, 1, 0)  MM(bA, 0)                     // ph0:  ih ks0 n01
      LOADB(bA, WihB, 1, 2)  MM(bB, 2)                     // ph1:  ih ks0 n23
      LOADA(xp, 1)  LOADB(bB, WihB, 2, 0)  MM(bC, 0)       // ph2:  ih ks1 n01
      LOADB(bC, WihB, 2, 2)  MM(bA, 2)                     // ph3:  ih ks1 n23
      LOADA(xp, 2)  LOADB(bA, WihB, 3, 0)  MM(bB, 0)       // ph4:  ih ks2 n01
      LOADB(bB, WihB, 3, 2)  MM(bC, 2)                     // ph5:  ih ks2 n23
      LOADA(xp, 3)  LOADB(bC, WhhB, 0, 0)  MM(bA, 0)       // ph6:  ih ks3 n01
      LOADB(bA, WhhB, 0, 2)  MM(bB, 2)                     // ph7:  ih ks3 n23
      LOADA(hp, 0)  LOADB(bB, WhhB, 1, 0)  MM(bC, 0)       // ph8:  hh ks0 n01
      LOADB(bC, WhhB, 1, 2)  MM(bA, 2)                     // ph9:  hh ks0 n23
      LOADA(hp, 1)  LOADB(bA, WhhB, 2, 0)  MM(bB, 0)       // ph10: hh ks1 n01
      LOADB(bB, WhhB, 2, 2)  MM(bC, 2)                     // ph11: hh ks1 n23
      LOADA(hp, 2)  LOADB(bC, WhhB, 3, 0)  MM(bA, 0)       // ph12: hh ks2 n01
      LOADB(bA, WhhB, 3, 2)  MM(bB, 2)                     // ph13: hh ks2 n23
      LOADA(hp, 3)  MM(bC, 0)                              // ph14: hh ks3 n01
      MM(bA, 2)                                            // ph15: hh ks3 n23

      // in-register epilogue: C/D row = quad*4 + r (node), this lane's dim fixed;
      // cell state flows through cst_l[ci][tid] (LDS, own column, no races)
      u16* hcur = layer ? h1s[wp] : h0s[wp];
      #pragma unroll
      for(int mt = 0; mt < 2; mt++){
        #pragma unroll
        for(int r = 0; r < 4; r++){
          const int node = mt * 16 + quad * 4 + r;
          const float gi = acc[mt][0][r];
          const float gf = acc[mt][1][r];
          const float gg = acc[mt][2][r];
          const float go = acc[mt][3][r];
          const int ci = layer * 8 + mt * 4 + r;
          const float c = sigf(gf) * cst_l[ci][tid] + sigf(gi) * tanhfast(gg);
          cst_l[ci][tid] = c;
          const float hv = sigf(go) * tanhfast(c);
          hcur[node * HPAD + dim] = f2bf(hv);
          if(layer == 1 && t == T_ - 1)
            hfin[node * 129 + dim] = hv;
        }
      }
      // after layer 1: copy next timestep's x-tile (barrier below covers it)
      if(layer == 1 && t < T_ - 1){
        const u16* src = spat + (size_t)((t + 1) * NTOT + n0) * H_;
        const int r = tid >> 4, c = tid & 15;
        *(uint4*)(xin + r * HPAD + c * 8) = *(const uint4*)(src + r * 128 + c * 8);
      }
      __syncthreads();
    }
  }
#undef MM
#undef LOADA
#undef LOADB

  // ---- fused LayerNorm: 16 threads per node, 8 dims each, fp32 from hfin ----
  {
    const int node = tid >> 4;
    const int c0 = (tid & 15) * 8;
    float v[8];
    #pragma unroll
    for(int j = 0; j < 8; j++) v[j] = hfin[node * 129 + c0 + j];
    float s = 0.f;
    #pragma unroll
    for(int j = 0; j < 8; j++) s += v[j];
    #pragma unroll
    for(int m = 8; m >= 1; m >>= 1) s += __shfl_xor(s, m);
    const float mu = s * (1.f / H_);
    float q = 0.f;
    #pragma unroll
    for(int j = 0; j < 8; j++){ const float d = v[j] - mu; q += d * d; }
    #pragma unroll
    for(int m = 8; m >= 1; m >>= 1) q += __shfl_xor(q, m);
    const float rstd = rsqrtf(q * (1.f / H_) + 1e-5f);
    #pragma unroll
    for(int j = 0; j < 8; j++)
      out[(size_t)(n0 + node) * H_ + c0 + j] = (v[j] - mu) * rstd * lng[c0 + j] + lnb[c0 + j];
  }
}

extern "C" void kernel_launch(void* const* d_in, const int* in_sizes, int n_in,
                              void* d_out, int out_size, void* d_ws, size_t ws_size,
                              hipStream_t stream) {
  (void)in_sizes; (void)n_in; (void)out_size; (void)ws_size;
  const float* x     = (const float*)d_in[0];
  const float* W     = (const float*)d_in[1];
  const float* att_s = (const float*)d_in[2];
  const float* att_d = (const float*)d_in[3];
  const float* gbias = (const float*)d_in[4];
  const float* Wih0  = (const float*)d_in[5];
  const float* Whh0  = (const float*)d_in[6];
  const float* bih0  = (const float*)d_in[7];
  const float* bhh0  = (const float*)d_in[8];
  const float* Wih1  = (const float*)d_in[9];
  const float* Whh1  = (const float*)d_in[10];
  const float* bih1  = (const float*)d_in[11];
  const float* bhh1  = (const float*)d_in[12];
  const float* lng   = (const float*)d_in[13];
  const float* lnb   = (const float*)d_in[14];
  const int*   ei    = (const int*)d_in[15];
  float* out = (float*)d_out;

  char* p = (char*)d_ws;
  auto carve = [&](size_t bytes) -> void* {
    void* r = (void*)p;
    p += (bytes + 255) & ~(size_t)255;
    return r;
  };
  u16* Wp_ih0 = (u16*)carve(512 * 128 * 2);
  u16* Wp_hh0 = (u16*)carve(512 * 128 * 2);
  u16* Wp_ih1 = (u16*)carve(512 * 128 * 2);
  u16* Wp_hh1 = (u16*)carve(512 * 128 * 2);
  u16* Wt     = (u16*)carve(H_ * F_ * 2);
  u16*   hbuf   = (u16*)carve((size_t)T_ * NTOT * H_ * 2);           // 21 MB bf16
  float* asrc   = (float*)carve((size_t)T_ * NTOT * NHEADS * 4);
  float* adst   = (float*)carve((size_t)T_ * NTOT * NHEADS * 4);
  u16*   spat   = (u16*)carve((size_t)T_ * NTOT * H_ * 2);           // 21 MB bf16
  int*   cnt    = (int*)carve(NTOT * 4);
  int*   curs   = (int*)carve(NTOT * 4);
  int*   rowst  = (int*)carve((NTOT + 1) * 4);
  int*   csr    = (int*)carve((size_t)E_ * 4);
  int*   csrd   = (int*)carve((size_t)E_ * 4);

  hipLaunchKernelGGL(k_init,  dim3(32),        dim3(256),  0, stream, cnt);
  hipLaunchKernelGGL(k_count, dim3(256),       dim3(256),  0, stream, ei, cnt);
  hipLaunchKernelGGL(k_scan,  dim3(1),         dim3(1024), 0, stream, cnt, rowst, curs);
  hipLaunchKernelGGL(k_fill,  dim3(256),       dim3(256),  0, stream, ei, rowst, curs, csr, csrd);
  hipLaunchKernelGGL(k_wconv, dim3(256, 5),    dim3(256),  0, stream,
                     Wih0, Wp_ih0, Whh0, Wp_hh0, Wih1, Wp_ih1, Whh1, Wp_hh1, W, Wt);
  hipLaunchKernelGGL(k_projm, dim3(1280),      dim3(256),  0, stream, x, Wt, att_s, att_d, hbuf, asrc, adst);
  hipLaunchKernelGGL(k_gat,   dim3(20480),     dim3(256),  0, stream, hbuf, asrc, adst, rowst, csr, gbias, spat);
  hipLaunchKernelGGL(k_lstm,  dim3(256),       dim3(512),  0, stream, spat,
                     Wp_ih0, Wp_hh0, bih0, bhh0, Wp_ih1, Wp_hh1, bih1, bhh1, lng, lnb, out);
}

// Round 25
// 292.917 us; speedup vs baseline: 1.0470x; 1.0470x over previous
//
#include <hip/hip_runtime.h>

#define T_ 10
#define B_ 4
#define N_ 2048
#define NTOT 8192
#define F_ 64
#define H_ 128
#define NHEADS 4
#define D_ 32
#define E_ 65536
#define EF 73728          // E + NTOT self-loops
#define HPAD 136

typedef __bf16 bf16x8 __attribute__((ext_vector_type(8)));
typedef float f32x4 __attribute__((ext_vector_type(4)));
typedef unsigned short u16;
typedef unsigned int u32;

__device__ __forceinline__ float bf2f(u16 u){
  union { unsigned int i; float f; } v; v.i = ((unsigned int)u) << 16; return v.f;
}
__device__ __forceinline__ u16 f2bf(float f){
  union { float f; unsigned int i; } v; v.f = f;
  return (u16)((v.i + 0x7FFFu + ((v.i >> 16) & 1u)) >> 16);
}
__device__ __forceinline__ float rcpf(float x){ return __builtin_amdgcn_rcpf(x); }
__device__ __forceinline__ float sigf(float x){ return rcpf(1.f + __expf(-x)); }
__device__ __forceinline__ float tanhfast(float x){ return 1.f - 2.f * rcpf(__expf(2.f * x) + 1.f); }
__device__ __forceinline__ float lrelu(float x){ return x > 0.f ? x : 0.2f * x; }

// ---------------- prep: weight conversions (y=0..4) + cnt zero (y=5) ----------------
__global__ __launch_bounds__(256) void k_prep(const float* __restrict__ s0, u16* __restrict__ d0,
                                              const float* __restrict__ s1, u16* __restrict__ d1,
                                              const float* __restrict__ s2, u16* __restrict__ d2,
                                              const float* __restrict__ s3, u16* __restrict__ d3,
                                              const float* __restrict__ W, u16* __restrict__ Wt,
                                              int* __restrict__ cnt){
  int i = blockIdx.x * 256 + threadIdx.x;
  if(blockIdx.y == 5){
    if(i < NTOT) cnt[i] = 0;
    return;
  }
  if(blockIdx.y == 4){
    if(i < H_ * F_){
      int nn = i >> 6, f = i & 63;
      Wt[i] = f2bf(W[f * H_ + nn]);
    }
    return;
  }
  const float* src = blockIdx.y == 0 ? s0 : blockIdx.y == 1 ? s1 : blockIdx.y == 2 ? s2 : s3;
  u16* dst = blockIdx.y == 0 ? d0 : blockIdx.y == 1 ? d1 : blockIdx.y == 2 ? d2 : d3;
  if(i < 512 * 128){
    int p = i >> 7, k = i & 127;
    int w = p >> 6, g = (p >> 4) & 3, l = p & 15;
    int row = g * 128 + w * 16 + l;
    dst[i] = f2bf(src[row * 128 + k]);
  }
}

__global__ __launch_bounds__(1024) void k_scan(const int* __restrict__ cnt,
                                               int* __restrict__ rowst,
                                               int* __restrict__ cursor){
  __shared__ int lds[1024];
  const int t = threadIdx.x;
  int loc[8];
  int s = 0;
  #pragma unroll
  for(int i = 0; i < 8; i++){ loc[i] = s; s += cnt[t * 8 + i]; }
  lds[t] = s;
  __syncthreads();
  for(int off = 1; off < 1024; off <<= 1){
    int v = lds[t];
    int a = (t >= off) ? lds[t - off] : 0;
    __syncthreads();
    lds[t] = v + a;
    __syncthreads();
  }
  const int base = (t > 0) ? lds[t - 1] : 0;
  #pragma unroll
  for(int i = 0; i < 8; i++){
    rowst[t * 8 + i] = base + loc[i];
    cursor[t * 8 + i] = 0;
  }
  if(t == 1023) rowst[NTOT] = lds[1023];
}

__global__ __launch_bounds__(256) void k_fill(const int* __restrict__ ei,
                                              const int* __restrict__ rowst,
                                              int* __restrict__ cursor,
                                              int* __restrict__ csr,
                                              int* __restrict__ csr_dst){
  int e = blockIdx.x * 256 + threadIdx.x;
  if(e < E_){
    int d = ei[E_ + e];
    int pos = atomicAdd(&cursor[d], 1);
    csr[rowst[d] + pos] = ei[e];
    csr_dst[rowst[d] + pos] = d;
  }
}

// ---------------- count (blocks >=1280) + MFMA GAT projection (blocks <1280) ----------------
__global__ __launch_bounds__(256) void k_cp(const float* __restrict__ x,
    const u16* __restrict__ Wt, const float* __restrict__ att_s, const float* __restrict__ att_d,
    u16* __restrict__ hbuf, float* __restrict__ asrc, float* __restrict__ adst,
    const int* __restrict__ ei, int* __restrict__ cnt){
  const int tid  = threadIdx.x;
  if(blockIdx.x >= 1280){
    const int e = (blockIdx.x - 1280) * 256 + tid;
    if(e < E_) atomicAdd(&cnt[ei[E_ + e]], 1);
    return;
  }
  const int wave = tid >> 6;
  const int lane = tid & 63;
  const int l15  = lane & 15;
  const int quad = lane >> 4;
  const int r0   = blockIdx.x * 64 + wave * 16;
  const int row  = r0 + l15;
  const int t = row >> 13, nt = row & 8191;
  const int b = nt >> 11, n = nt & 2047;
  const float* xrow = x + (((size_t)b * T_ + t) * N_ + n) * F_;

  bf16x8 a[2];
  #pragma unroll
  for(int ks = 0; ks < 2; ks++){
    const float4 f0 = *(const float4*)(xrow + ks * 32 + quad * 8);
    const float4 f1 = *(const float4*)(xrow + ks * 32 + quad * 8 + 4);
    bf16x8 av;
    av[0] = (__bf16)f0.x; av[1] = (__bf16)f0.y; av[2] = (__bf16)f0.z; av[3] = (__bf16)f0.w;
    av[4] = (__bf16)f1.x; av[5] = (__bf16)f1.y; av[6] = (__bf16)f1.z; av[7] = (__bf16)f1.w;
    a[ks] = av;
  }

  f32x4 acc[8];
  #pragma unroll
  for(int c = 0; c < 8; c++){ f32x4 z = {0.f,0.f,0.f,0.f}; acc[c] = z; }
  #pragma unroll
  for(int c = 0; c < 8; c++){
    #pragma unroll
    for(int ks = 0; ks < 2; ks++){
      const bf16x8 bv = *(const bf16x8*)(Wt + (c * 16 + l15) * F_ + ks * 32 + quad * 8);
      acc[c] = __builtin_amdgcn_mfma_f32_16x16x32_bf16(a[ks], bv, acc[c], 0, 0, 0);
    }
  }

  float ps[4][4], pd[4][4];   // [r][head]
  #pragma unroll
  for(int r = 0; r < 4; r++)
    #pragma unroll
    for(int h = 0; h < 4; h++){ ps[r][h] = 0.f; pd[r][h] = 0.f; }

  #pragma unroll
  for(int c = 0; c < 8; c++){
    const int col = c * 16 + l15;
    const float asv = att_s[col];
    const float adv = att_d[col];
    const int head = c >> 1;
    #pragma unroll
    for(int r = 0; r < 4; r++){
      const float v = acc[c][r];
      hbuf[(size_t)(r0 + quad * 4 + r) * H_ + col] = f2bf(v);
      ps[r][head] += v * asv;
      pd[r][head] += v * adv;
    }
  }
  #pragma unroll
  for(int m = 8; m >= 1; m >>= 1){
    #pragma unroll
    for(int r = 0; r < 4; r++)
      #pragma unroll
      for(int h = 0; h < 4; h++){
        ps[r][h] += __shfl_xor(ps[r][h], m);
        pd[r][h] += __shfl_xor(pd[r][h], m);
      }
  }
  if(l15 == 0){
    #pragma unroll
    for(int r = 0; r < 4; r++){
      const int rw = r0 + quad * 4 + r;
      #pragma unroll
      for(int h = 0; h < 4; h++){
        asrc[(size_t)rw * NHEADS + h] = ps[r][h];
        adst[(size_t)rw * NHEADS + h] = pd[r][h];
      }
    }
  }
}

// ---------------- fused GAT softmax + aggregation (v3: single-pass, no-max; R20 best) ------------
__global__ __launch_bounds__(256) void k_gat(const u16* __restrict__ hbuf,
    const float* __restrict__ asrc, const float* __restrict__ adst,
    const int* __restrict__ rowst, const int* __restrict__ csr,
    const float* __restrict__ gbias, u16* __restrict__ spat){
  __shared__ float exl[4][64][4];   // per-wave edge numerators
  __shared__ int   sxl[4][64];      // per-wave edge sources
  const int tid = threadIdx.x;
  const int wave = tid >> 6;
  const int lane = tid & 63;
  const int task = blockIdx.x * 4 + wave;
  const int node = task & 8191;
  const int t = task >> 13;
  const int rbase = t * NTOT;
  const int rs = rowst[node], re = rowst[node + 1];

  const float4 ad4  = *(const float4*)&adst[(size_t)(rbase + node) * NHEADS];
  const float4 ass4 = *(const float4*)&asrc[(size_t)(rbase + node) * NHEADS];
  const float xs0 = __expf(lrelu(ass4.x + ad4.x));
  const float xs1 = __expf(lrelu(ass4.y + ad4.y));
  const float xs2 = __expf(lrelu(ass4.z + ad4.z));
  const float xs3 = __expf(lrelu(ass4.w + ad4.w));

  const int dlo = lane, dhi = lane + 64;
  float den0 = 0.f, den1 = 0.f, den2 = 0.f, den3 = 0.f;
  float accR0 = 0.f, accR1 = 0.f;
  for(int base = rs; base < re; base += 64){
    const int i = base + lane;
    float ex0 = 0.f, ex1 = 0.f, ex2 = 0.f, ex3 = 0.f;
    int sv = 0;
    if(i < re){
      sv = csr[i];
      const float4 a2 = *(const float4*)&asrc[(size_t)(rbase + sv) * NHEADS];
      ex0 = __expf(lrelu(a2.x + ad4.x)); ex1 = __expf(lrelu(a2.y + ad4.y));
      ex2 = __expf(lrelu(a2.z + ad4.z)); ex3 = __expf(lrelu(a2.w + ad4.w));
      den0 += ex0; den1 += ex1; den2 += ex2; den3 += ex3;
    }
    exl[wave][lane][0] = ex0; exl[wave][lane][1] = ex1;
    exl[wave][lane][2] = ex2; exl[wave][lane][3] = ex3;
    sxl[wave][lane] = sv;
    __asm__ volatile("s_waitcnt lgkmcnt(0)" ::: "memory");
    __builtin_amdgcn_sched_barrier(0);
    const int lim = (re - base < 64) ? (re - base) : 64;
    for(int j = 0; j < lim; j++){
      const int s = sxl[wave][j];
      const float exA = lane < 32 ? exl[wave][j][0] : exl[wave][j][1];
      const float exB = lane < 32 ? exl[wave][j][2] : exl[wave][j][3];
      accR0 += exA * bf2f(hbuf[(size_t)(rbase + s) * H_ + dlo]);
      accR1 += exB * bf2f(hbuf[(size_t)(rbase + s) * H_ + dhi]);
    }
  }
  #pragma unroll
  for(int msk = 32; msk >= 1; msk >>= 1){
    den0 += __shfl_xor(den0, msk); den1 += __shfl_xor(den1, msk);
    den2 += __shfl_xor(den2, msk); den3 += __shfl_xor(den3, msk);
  }
  den0 += xs0; den1 += xs1; den2 += xs2; den3 += xs3;

  const float rdA = rcpf(lane < 32 ? den0 : den1);
  const float rdB = rcpf(lane < 32 ? den2 : den3);
  const float xsA = lane < 32 ? xs0 : xs1;
  const float xsB = lane < 32 ? xs2 : xs3;
  accR0 += xsA * bf2f(hbuf[(size_t)(rbase + node) * H_ + dlo]);
  accR1 += xsB * bf2f(hbuf[(size_t)(rbase + node) * H_ + dhi]);
  const float v0 = accR0 * rdA + gbias[dlo];
  const float v1 = accR1 * rdB + gbias[dhi];
  spat[(size_t)(rbase + node) * H_ + dlo] = f2bf(v0 > 0.f ? v0 : 0.f);
  spat[(size_t)(rbase + node) * H_ + dhi] = f2bf(v1 > 0.f ? v1 : 0.f);
}

// ---------------- 2-layer LSTM: R14 best (3-bank/16-phase, cst/bias in LDS) ------
// FROZEN at 133us (R19 proved the 197MB scratch is latency-hidden; clean-memory
// variant was SLOWER at 144us — barrier chain is the floor for this shape).
__global__ __launch_bounds__(512) void k_lstm(
    const u16* __restrict__ spat,
    const u16* __restrict__ Wp_ih0, const u16* __restrict__ Wp_hh0,
    const float* __restrict__ bih0, const float* __restrict__ bhh0,
    const u16* __restrict__ Wp_ih1, const u16* __restrict__ Wp_hh1,
    const float* __restrict__ bih1, const float* __restrict__ bhh1,
    const float* __restrict__ lng, const float* __restrict__ lnb,
    float* __restrict__ out)
{
  __shared__ __align__(16) u16 xin[32 * HPAD];               // 8.5 KB
  __shared__ __align__(16) u16 h0s[2][32 * HPAD];            // 17 KB
  __shared__ __align__(16) u16 h1s[2][32 * HPAD];            // 17 KB
  __shared__ __align__(16) float hfin[32 * 129];             // 16.5 KB fp32 final h1
  __shared__ float cst_l[16][512];                           // 32 KB per-thread cell state
  __shared__ float bias_l[8][512];                           // 16 KB per-thread gate bias

  const int tid  = threadIdx.x;
  const int wave = tid >> 6;
  const int lane = tid & 63;
  const int l15  = lane & 15;
  const int quad = lane >> 4;
  const int n0   = blockIdx.x * 32;
  const int dim  = wave * 16 + l15;

  for(int i = tid; i < 2 * 32 * HPAD; i += 512){
    ((u16*)h0s)[i] = 0; ((u16*)h1s)[i] = 0;
  }
  // xin(t=0): 32 rows x 16 chunks of 16B = 512 chunks = one pass of 512 threads
  {
    const u16* src = spat + (size_t)n0 * H_;
    const int r = tid >> 4, c = tid & 15;
    *(uint4*)(xin + r * HPAD + c * 8) = *(const uint4*)(src + r * 128 + c * 8);
  }
  #pragma unroll
  for(int i = 0; i < 16; i++) cst_l[i][tid] = 0.f;
  #pragma unroll
  for(int g = 0; g < 4; g++){
    bias_l[g][tid]     = bih0[g * 128 + dim] + bhh0[g * 128 + dim];
    bias_l[4 + g][tid] = bih1[g * 128 + dim] + bhh1[g * 128 + dim];
  }
  __syncthreads();

  // lane's fragment base: rows wave*64 + nt*16 + l15 of the gate-permuted matrix,
  // elements quad*8..quad*8+7 of k-slice ks -> Wm[fbase + nt*2048 + ks*32]
  const size_t fbase = (size_t)(wave * 64 + l15) * 128 + quad * 8;

// 3-bank/16-phase pipeline pieces. All indices compile-time static (rule #20).
#define LOADB(BK, MATB, KS, NTO)                                          \
    BK[0] = *(const bf16x8*)((MATB) + (NTO) * 2048 + (KS) * 32);          \
    BK[1] = *(const bf16x8*)((MATB) + ((NTO) + 1) * 2048 + (KS) * 32);

#define LOADA(AP, KS)                                                     \
    a0 = *(const bf16x8*)((AP) + l15 * HPAD + (KS) * 32 + quad * 8);      \
    a1 = *(const bf16x8*)((AP) + (16 + l15) * HPAD + (KS) * 32 + quad * 8);

#define MM(BK, NTO)                                                                             \
    acc[0][NTO]       = __builtin_amdgcn_mfma_f32_16x16x32_bf16(a0, BK[0], acc[0][NTO], 0, 0, 0);       \
    acc[1][NTO]       = __builtin_amdgcn_mfma_f32_16x16x32_bf16(a1, BK[0], acc[1][NTO], 0, 0, 0);       \
    acc[0][(NTO) + 1] = __builtin_amdgcn_mfma_f32_16x16x32_bf16(a0, BK[1], acc[0][(NTO) + 1], 0, 0, 0); \
    acc[1][(NTO) + 1] = __builtin_amdgcn_mfma_f32_16x16x32_bf16(a1, BK[1], acc[1][(NTO) + 1], 0, 0, 0); \
    __builtin_amdgcn_sched_barrier(0);

  #pragma unroll 1
  for(int t = 0; t < T_; t++){
    const int rp = t & 1, wp = rp ^ 1;
    #pragma unroll
    for(int layer = 0; layer < 2; layer++){
      const u16* Wih = layer ? Wp_ih1 : Wp_ih0;
      const u16* Whh = layer ? Wp_hh1 : Wp_hh0;
      const u16* xp  = layer ? h0s[wp] : xin;      // a-input, x-part (phases 0-7)
      const u16* hp  = layer ? h1s[rp] : h0s[rp];  // a-input, h-part (phases 8-15)

      f32x4 acc[2][4];
      #pragma unroll
      for(int nt = 0; nt < 4; nt++){
        const float bv = bias_l[layer * 4 + nt][tid];
        f32x4 b4 = {bv, bv, bv, bv};
        acc[0][nt] = b4; acc[1][nt] = b4;
      }

      const u16* WihB = Wih + fbase;
      const u16* WhhB = Whh + fbase;
      bf16x8 bA[2], bB[2], bC[2];
      bf16x8 a0, a1;

      // prologue: first two banks + ks0 a-frags
      LOADB(bA, WihB, 0, 0)  LOADB(bB, WihB, 0, 2)  LOADA(xp, 0)
      // 16 phases; bank loaded at phase p is consumed at p+2
      LOADB(bC, WihB, 1, 0)  MM(bA, 0)                     // ph0:  ih ks0 n01
      LOADB(bA, WihB, 1, 2)  MM(bB, 2)                     // ph1:  ih ks0 n23
      LOADA(xp, 1)  LOADB(bB, WihB, 2, 0)  MM(bC, 0)       // ph2:  ih ks1 n01
      LOADB(bC, WihB, 2, 2)  MM(bA, 2)                     // ph3:  ih ks1 n23
      LOADA(xp, 2)  LOADB(bA, WihB, 3, 0)  MM(bB, 0)       // ph4:  ih ks2 n01
      LOADB(bB, WihB, 3, 2)  MM(bC, 2)                     // ph5:  ih ks2 n23
      LOADA(xp, 3)  LOADB(bC, WhhB, 0, 0)  MM(bA, 0)       // ph6:  ih ks3 n01
      LOADB(bA, WhhB, 0, 2)  MM(bB, 2)                     // ph7:  ih ks3 n23
      LOADA(hp, 0)  LOADB(bB, WhhB, 1, 0)  MM(bC, 0)       // ph8:  hh ks0 n01
      LOADB(bC, WhhB, 1, 2)  MM(bA, 2)                     // ph9:  hh ks0 n23
      LOADA(hp, 1)  LOADB(bA, WhhB, 2, 0)  MM(bB, 0)       // ph10: hh ks1 n01
      LOADB(bB, WhhB, 2, 2)  MM(bC, 2)                     // ph11: hh ks1 n23
      LOADA(hp, 2)  LOADB(bC, WhhB, 3, 0)  MM(bA, 0)       // ph12: hh ks2 n01
      LOADB(bA, WhhB, 3, 2)  MM(bB, 2)                     // ph13: hh ks2 n23
      LOADA(hp, 3)  MM(bC, 0)                              // ph14: hh ks3 n01
      MM(bA, 2)                                            // ph15: hh ks3 n23

      // in-register epilogue: C/D row = quad*4 + r (node), this lane's dim fixed;
      // cell state flows through cst_l[ci][tid] (LDS, own column, no races)
      u16* hcur = layer ? h1s[wp] : h0s[wp];
      #pragma unroll
      for(int mt = 0; mt < 2; mt++){
        #pragma unroll
        for(int r = 0; r < 4; r++){
          const int node = mt * 16 + quad * 4 + r;
          const float gi = acc[mt][0][r];
          const float gf = acc[mt][1][r];
          const float gg = acc[mt][2][r];
          const float go = acc[mt][3][r];
          const int ci = layer * 8 + mt * 4 + r;
          const float c = sigf(gf) * cst_l[ci][tid] + sigf(gi) * tanhfast(gg);
          cst_l[ci][tid] = c;
          const float hv = sigf(go) * tanhfast(c);
          hcur[node * HPAD + dim] = f2bf(hv);
          if(layer == 1 && t == T_ - 1)
            hfin[node * 129 + dim] = hv;
        }
      }
      // after layer 1: copy next timestep's x-tile (barrier below covers it)
      if(layer == 1 && t < T_ - 1){
        const u16* src = spat + (size_t)((t + 1) * NTOT + n0) * H_;
        const int r = tid >> 4, c = tid & 15;
        *(uint4*)(xin + r * HPAD + c * 8) = *(const uint4*)(src + r * 128 + c * 8);
      }
      __syncthreads();
    }
  }
#undef MM
#undef LOADA
#undef LOADB

  // ---- fused LayerNorm: 16 threads per node, 8 dims each, fp32 from hfin ----
  {
    const int node = tid >> 4;
    const int c0 = (tid & 15) * 8;
    float v[8];
    #pragma unroll
    for(int j = 0; j < 8; j++) v[j] = hfin[node * 129 + c0 + j];
    float s = 0.f;
    #pragma unroll
    for(int j = 0; j < 8; j++) s += v[j];
    #pragma unroll
    for(int m = 8; m >= 1; m >>= 1) s += __shfl_xor(s, m);
    const float mu = s * (1.f / H_);
    float q = 0.f;
    #pragma unroll
    for(int j = 0; j < 8; j++){ const float d = v[j] - mu; q += d * d; }
    #pragma unroll
    for(int m = 8; m >= 1; m >>= 1) q += __shfl_xor(q, m);
    const float rstd = rsqrtf(q * (1.f / H_) + 1e-5f);
    #pragma unroll
    for(int j = 0; j < 8; j++)
      out[(size_t)(n0 + node) * H_ + c0 + j] = (v[j] - mu) * rstd * lng[c0 + j] + lnb[c0 + j];
  }
}

extern "C" void kernel_launch(void* const* d_in, const int* in_sizes, int n_in,
                              void* d_out, int out_size, void* d_ws, size_t ws_size,
                              hipStream_t stream) {
  (void)in_sizes; (void)n_in; (void)out_size; (void)ws_size;
  const float* x     = (const float*)d_in[0];
  const float* W     = (const float*)d_in[1];
  const float* att_s = (const float*)d_in[2];
  const float* att_d = (const float*)d_in[3];
  const float* gbias = (const float*)d_in[4];
  const float* Wih0  = (const float*)d_in[5];
  const float* Whh0  = (const float*)d_in[6];
  const float* bih0  = (const float*)d_in[7];
  const float* bhh0  = (const float*)d_in[8];
  const float* Wih1  = (const float*)d_in[9];
  const float* Whh1  = (const float*)d_in[10];
  const float* bih1  = (const float*)d_in[11];
  const float* bhh1  = (const float*)d_in[12];
  const float* lng   = (const float*)d_in[13];
  const float* lnb   = (const float*)d_in[14];
  const int*   ei    = (const int*)d_in[15];
  float* out = (float*)d_out;

  char* p = (char*)d_ws;
  auto carve = [&](size_t bytes) -> void* {
    void* r = (void*)p;
    p += (bytes + 255) & ~(size_t)255;
    return r;
  };
  u16* Wp_ih0 = (u16*)carve(512 * 128 * 2);
  u16* Wp_hh0 = (u16*)carve(512 * 128 * 2);
  u16* Wp_ih1 = (u16*)carve(512 * 128 * 2);
  u16* Wp_hh1 = (u16*)carve(512 * 128 * 2);
  u16* Wt     = (u16*)carve(H_ * F_ * 2);
  u16*   hbuf   = (u16*)carve((size_t)T_ * NTOT * H_ * 2);           // 21 MB bf16
  float* asrc   = (float*)carve((size_t)T_ * NTOT * NHEADS * 4);
  float* adst   = (float*)carve((size_t)T_ * NTOT * NHEADS * 4);
  u16*   spat   = (u16*)carve((size_t)T_ * NTOT * H_ * 2);           // 21 MB bf16
  int*   cnt    = (int*)carve(NTOT * 4);
  int*   curs   = (int*)carve(NTOT * 4);
  int*   rowst  = (int*)carve((NTOT + 1) * 4);
  int*   csr    = (int*)carve((size_t)E_ * 4);
  int*   csrd   = (int*)carve((size_t)E_ * 4);

  hipLaunchKernelGGL(k_prep,  dim3(256, 6),    dim3(256),  0, stream,
                     Wih0, Wp_ih0, Whh0, Wp_hh0, Wih1, Wp_ih1, Whh1, Wp_hh1, W, Wt, cnt);
  hipLaunchKernelGGL(k_cp,    dim3(1536),      dim3(256),  0, stream,
                     x, Wt, att_s, att_d, hbuf, asrc, adst, ei, cnt);
  hipLaunchKernelGGL(k_scan,  dim3(1),         dim3(1024), 0, stream, cnt, rowst, curs);
  hipLaunchKernelGGL(k_fill,  dim3(256),       dim3(256),  0, stream, ei, rowst, curs, csr, csrd);
  hipLaunchKernelGGL(k_gat,   dim3(20480),     dim3(256),  0, stream, hbuf, asrc, adst, rowst, csr, gbias, spat);
  hipLaunchKernelGGL(k_lstm,  dim3(256),       dim3(512),  0, stream, spat,
                     Wp_ih0, Wp_hh0, bih0, bhh0, Wp_ih1, Wp_hh1, bih1, bhh1, lng, lnb, out);
}